// Round 3
// baseline (819.237 us; speedup 1.0000x reference)
//
#include <hip/hip_runtime.h>

typedef unsigned short u16;
typedef unsigned int u32;
typedef __attribute__((ext_vector_type(8))) short bf16x8;
typedef __attribute__((ext_vector_type(4))) float f32x4;

#define LDK 72   // stage-1 LDS stride (64 + 8 pad)

__device__ __forceinline__ u16 f2bf(float f) {
    u32 u = __float_as_uint(f);
    u += 0x7fffu + ((u >> 16) & 1u);   // round-to-nearest-even
    return (u16)(u >> 16);
}

// ---------------- prep kernels ----------------

__global__ __launch_bounds__(256) void prep_u_kernel(
    const float* __restrict__ w_num, const float* __restrict__ b_num,
    const float* __restrict__ W_first, float* __restrict__ U, float* __restrict__ P)
{
    __shared__ float wrow[256];
    __shared__ float brow[256];
    int j = threadIdx.x, f = blockIdx.x;
    wrow[j] = w_num[f * 256 + j];
    brow[j] = b_num[f * 256 + j];
    __syncthreads();
    float au = 0.f, ap = 0.f;
    for (int k = 0; k < 256; k++) {
        float w = W_first[(size_t)((f << 8) + k) * 256 + j];
        au = fmaf(wrow[k], w, au);
        ap = fmaf(brow[k], w, ap);
    }
    U[f * 256 + j] = au;
    P[f * 256 + j] = ap;
}

__global__ __launch_bounds__(256) void prep_c0_kernel(
    const float* __restrict__ b_first, const float* __restrict__ P, float* __restrict__ c0)
{
    int j = threadIdx.x;
    float a = b_first[j];
    for (int f = 0; f < 32; f++) a += P[f * 256 + j];
    c0[j] = a;
}

// WcT[j][k] (256 x 4160 bf16): k<4096 -> W_first[8192+k][j]; k<4128 -> U[k-4096][j]; else 0
__global__ __launch_bounds__(256) void prep_wcat_kernel(
    const float* __restrict__ W_first, const float* __restrict__ U, u16* __restrict__ WcT)
{
    int k = blockIdx.x;   // 0..4159
    int j = threadIdx.x;  // 0..255
    float v;
    if (k < 4096)      v = W_first[(size_t)(8192 + k) * 256 + j];
    else if (k < 4128) v = U[(k - 4096) * 256 + j];
    else               v = 0.f;
    WcT[(size_t)j * 4160 + k] = f2bf(v);
}

__global__ __launch_bounds__(256) void prep_w1t_kernel(
    const float* __restrict__ W1s, u16* __restrict__ W1T)
{
    int bk = blockIdx.x;             // l*256 + k
    int l = bk >> 8, k = bk & 255;
    int n = threadIdx.x;
    for (int h = 0; h < 2; h++) {
        int nn = n + h * 256;
        float v = W1s[(size_t)l * 131072 + (size_t)k * 512 + nn];
        W1T[(size_t)l * 131072 + (size_t)nn * 256 + k] = f2bf(v);
    }
}

__global__ __launch_bounds__(256) void prep_w2t_kernel(
    const float* __restrict__ W2s, u16* __restrict__ W2T)
{
    int bk = blockIdx.x;             // l*512 + k
    int l = bk >> 9, k = bk & 511;
    int n = threadIdx.x;
    float v = W2s[(size_t)l * 131072 + (size_t)k * 256 + n];
    W2T[(size_t)l * 131072 + (size_t)n * 512 + k] = f2bf(v);
}

// ---------------- mega kernel: whole network, 32 rows per block ----------------
// Stage 1: gathered first GEMM (K=4160) -> h_acc in registers (fp32)
// Stage 2: 8x { LN -> hn(LDS bf16) -> FC1+ReLU -> hid(LDS bf16) -> FC2 -> h_acc += }
// Stage 3: final LN + 256x2 head -> out
// h never touches global memory. Weights read direct global->VGPR (L2-resident).
__global__ __launch_bounds__(256, 3) void mega_kernel(
    const u16* __restrict__ WcT, const float* __restrict__ c0,
    const int* __restrict__ cidx, const float* __restrict__ cemb,
    const float* __restrict__ xnum,
    const float* __restrict__ ln_g, const float* __restrict__ ln_b,
    const u16* __restrict__ W1T, const float* __restrict__ b1s,
    const u16* __restrict__ W2T, const float* __restrict__ b2s,
    const float* __restrict__ g_f, const float* __restrict__ beta_f,
    const float* __restrict__ Wh, const float* __restrict__ bh,
    float* __restrict__ out)
{
    __shared__ __align__(16) char smem[51200];
    // stage-1 overlay
    u16*   Ab   = (u16*)smem;                 //  4608 B  (32 x 72)
    u16*   Bb   = (u16*)(smem + 4608);        // 36864 B  (256 x 72)
    int*   sidx = (int*)(smem + 41472);       //  2048 B
    float* sx   = (float*)(smem + 43520);     //  4096 B
    // stage-2 overlay
    u16*   hn   = (u16*)smem;                 // 16896 B  (32 x 264)
    u16*   hid  = (u16*)(smem + 16896);       // 33280 B  (32 x 520)
    float* red  = (float*)(smem + 50176);     //  1024 B  (256 f32)

    const int tid  = threadIdx.x;
    const int lane = tid & 63;
    const int wv   = tid >> 6;
    const int quad = lane >> 4;
    const int l16  = lane & 15;
    const int m0   = blockIdx.x * 32;

    // ---------- stage 1 ----------
#pragma unroll
    for (int i = 0; i < 2; i++) sidx[tid + i * 256] = cidx[m0 * 16 + tid + i * 256];
    {
        float4 v = *(const float4*)&xnum[(size_t)m0 * 32 + tid * 4];
        sx[tid * 4 + 0] = v.x; sx[tid * 4 + 1] = v.y;
        sx[tid * 4 + 2] = v.z; sx[tid * 4 + 3] = v.w;
    }
    __syncthreads();

    f32x4 h_acc[2][4];
#pragma unroll
    for (int i = 0; i < 2; i++)
#pragma unroll
        for (int j = 0; j < 4; j++) h_acc[i][j] = (f32x4){0.f, 0.f, 0.f, 0.f};

    for (int k0 = 0; k0 < 4160; k0 += 64) {
#pragma unroll
        for (int it = 0; it < 2; it++) {
            int chunk = tid + it * 256;   // 512 float4 chunks: 32 rows x 16
            int r = chunk >> 4;
            int c4 = chunk & 15;
            int k = k0 + c4 * 4;
            float4 v;
            if (k < 4096) {
                int f = k >> 8;
                int rowi = sidx[r * 16 + f];
                v = *(const float4*)&cemb[(size_t)rowi * 256 + (k & 255)];
            } else if (k < 4128) {
                int c = k - 4096;
                v.x = sx[r * 32 + c];     v.y = sx[r * 32 + c + 1];
                v.z = sx[r * 32 + c + 2]; v.w = sx[r * 32 + c + 3];
            } else {
                v = make_float4(0.f, 0.f, 0.f, 0.f);
            }
            u16* dst = &Ab[r * LDK + c4 * 4];
            dst[0] = f2bf(v.x); dst[1] = f2bf(v.y);
            dst[2] = f2bf(v.z); dst[3] = f2bf(v.w);
        }
#pragma unroll
        for (int it = 0; it < 8; it++) {
            int chunk = tid + it * 256;   // 2048 chunks: 256 n-rows x 8
            int r = chunk >> 3;
            int c8 = chunk & 7;
            *(bf16x8*)&Bb[r * LDK + c8 * 8] =
                *(const bf16x8*)&WcT[(size_t)r * 4160 + k0 + c8 * 8];
        }
        __syncthreads();
#pragma unroll
        for (int kk = 0; kk < 64; kk += 32) {
            bf16x8 af[2], bfr[4];
#pragma unroll
            for (int i = 0; i < 2; i++)
                af[i] = *(const bf16x8*)&Ab[(i * 16 + l16) * LDK + kk + quad * 8];
#pragma unroll
            for (int j = 0; j < 4; j++)
                bfr[j] = *(const bf16x8*)&Bb[(wv * 64 + j * 16 + l16) * LDK + kk + quad * 8];
#pragma unroll
            for (int i = 0; i < 2; i++)
#pragma unroll
                for (int j = 0; j < 4; j++)
                    h_acc[i][j] = __builtin_amdgcn_mfma_f32_16x16x32_bf16(
                        af[i], bfr[j], h_acc[i][j], 0, 0, 0);
        }
        __syncthreads();
    }
#pragma unroll
    for (int j = 0; j < 4; j++) {
        float c = c0[wv * 64 + j * 16 + l16];
#pragma unroll
        for (int i = 0; i < 2; i++)
#pragma unroll
            for (int r = 0; r < 4; r++) h_acc[i][j][r] += c;
    }

    // ---------- stage 2: 8 residual blocks ----------
    for (int l = 0; l < 8; l++) {
        // --- LN stats: per-row sum/sumsq across the 4 waves ---
#pragma unroll
        for (int i = 0; i < 2; i++)
#pragma unroll
            for (int r = 0; r < 4; r++) {
                float a = h_acc[i][0][r] + h_acc[i][1][r] + h_acc[i][2][r] + h_acc[i][3][r];
                float b = h_acc[i][0][r] * h_acc[i][0][r] + h_acc[i][1][r] * h_acc[i][1][r]
                        + h_acc[i][2][r] * h_acc[i][2][r] + h_acc[i][3][r] * h_acc[i][3][r];
#pragma unroll
                for (int o = 1; o < 16; o <<= 1) { a += __shfl_xor(a, o); b += __shfl_xor(b, o); }
                if (l16 == 0) {
                    int row = i * 16 + quad * 4 + r;
                    red[row * 4 + wv] = a;
                    red[128 + row * 4 + wv] = b;
                }
            }
        __syncthreads();
        float mu[2][4], rs[2][4];
#pragma unroll
        for (int i = 0; i < 2; i++)
#pragma unroll
            for (int r = 0; r < 4; r++) {
                int row = i * 16 + quad * 4 + r;
                float4 sv = *(const float4*)&red[row * 4];
                float4 qv = *(const float4*)&red[128 + row * 4];
                float st = sv.x + sv.y + sv.z + sv.w;
                float qt = qv.x + qv.y + qv.z + qv.w;
                float m = st * (1.f / 256.f);
                mu[i][r] = m;
                rs[i][r] = rsqrtf(qt * (1.f / 256.f) - m * m + 1e-5f);
            }
        // --- normalize -> hn (bf16) ---
        {
            float gv[4], bv[4];
#pragma unroll
            for (int j = 0; j < 4; j++) {
                int col = wv * 64 + j * 16 + l16;
                gv[j] = ln_g[l * 256 + col];
                bv[j] = ln_b[l * 256 + col];
            }
#pragma unroll
            for (int i = 0; i < 2; i++)
#pragma unroll
                for (int j = 0; j < 4; j++)
#pragma unroll
                    for (int r = 0; r < 4; r++) {
                        int row = i * 16 + quad * 4 + r;
                        float v = (h_acc[i][j][r] - mu[i][r]) * rs[i][r] * gv[j] + bv[j];
                        hn[row * 264 + wv * 64 + j * 16 + l16] = f2bf(v);
                    }
        }
        __syncthreads();

        // --- FC1: hid[32][512] = relu(hn @ W1 + b1), wave owns 128 cols ---
        const u16* W1 = W1T + (size_t)l * 131072;
        float b1v[8];
#pragma unroll
        for (int j = 0; j < 8; j++) b1v[j] = b1s[l * 512 + wv * 128 + j * 16 + l16];
        f32x4 acc1[2][8];
#pragma unroll
        for (int i = 0; i < 2; i++)
#pragma unroll
            for (int j = 0; j < 8; j++) acc1[i][j] = (f32x4){0.f, 0.f, 0.f, 0.f};
#pragma unroll
        for (int kk = 0; kk < 256; kk += 32) {
            bf16x8 af0 = *(const bf16x8*)&hn[(l16) * 264 + kk + quad * 8];
            bf16x8 af1 = *(const bf16x8*)&hn[(16 + l16) * 264 + kk + quad * 8];
            bf16x8 bw[8];
#pragma unroll
            for (int j = 0; j < 8; j++)
                bw[j] = *(const bf16x8*)&W1[(size_t)(wv * 128 + j * 16 + l16) * 256 + kk + quad * 8];
#pragma unroll
            for (int j = 0; j < 8; j++) {
                acc1[0][j] = __builtin_amdgcn_mfma_f32_16x16x32_bf16(af0, bw[j], acc1[0][j], 0, 0, 0);
                acc1[1][j] = __builtin_amdgcn_mfma_f32_16x16x32_bf16(af1, bw[j], acc1[1][j], 0, 0, 0);
            }
        }
#pragma unroll
        for (int i = 0; i < 2; i++)
#pragma unroll
            for (int j = 0; j < 8; j++)
#pragma unroll
                for (int r = 0; r < 4; r++) {
                    float v = acc1[i][j][r] + b1v[j];
                    v = v > 0.f ? v : 0.f;
                    hid[(i * 16 + quad * 4 + r) * 520 + wv * 128 + j * 16 + l16] = f2bf(v);
                }
        __syncthreads();

        // --- FC2: h_acc += hid @ W2 + b2, wave owns 64 cols ---
        const u16* W2 = W2T + (size_t)l * 131072;
        float b2v[4];
#pragma unroll
        for (int j = 0; j < 4; j++) b2v[j] = b2s[l * 256 + wv * 64 + j * 16 + l16];
        f32x4 acc2[2][4];
#pragma unroll
        for (int i = 0; i < 2; i++)
#pragma unroll
            for (int j = 0; j < 4; j++) acc2[i][j] = (f32x4){0.f, 0.f, 0.f, 0.f};
#pragma unroll
        for (int kk = 0; kk < 512; kk += 32) {
            bf16x8 af0 = *(const bf16x8*)&hid[(l16) * 520 + kk + quad * 8];
            bf16x8 af1 = *(const bf16x8*)&hid[(16 + l16) * 520 + kk + quad * 8];
            bf16x8 bw[4];
#pragma unroll
            for (int j = 0; j < 4; j++)
                bw[j] = *(const bf16x8*)&W2[(size_t)(wv * 64 + j * 16 + l16) * 512 + kk + quad * 8];
#pragma unroll
            for (int j = 0; j < 4; j++) {
                acc2[0][j] = __builtin_amdgcn_mfma_f32_16x16x32_bf16(af0, bw[j], acc2[0][j], 0, 0, 0);
                acc2[1][j] = __builtin_amdgcn_mfma_f32_16x16x32_bf16(af1, bw[j], acc2[1][j], 0, 0, 0);
            }
        }
#pragma unroll
        for (int i = 0; i < 2; i++)
#pragma unroll
            for (int j = 0; j < 4; j++)
#pragma unroll
                for (int r = 0; r < 4; r++)
                    h_acc[i][j][r] += acc2[i][j][r] + b2v[j];
        __syncthreads();   // protect hn (FC1 reads) & hid (FC2 reads) before next layer rewrites
    }

    // ---------- stage 3: final LN + head ----------
#pragma unroll
    for (int i = 0; i < 2; i++)
#pragma unroll
        for (int r = 0; r < 4; r++) {
            float a = h_acc[i][0][r] + h_acc[i][1][r] + h_acc[i][2][r] + h_acc[i][3][r];
            float b = h_acc[i][0][r] * h_acc[i][0][r] + h_acc[i][1][r] * h_acc[i][1][r]
                    + h_acc[i][2][r] * h_acc[i][2][r] + h_acc[i][3][r] * h_acc[i][3][r];
#pragma unroll
            for (int o = 1; o < 16; o <<= 1) { a += __shfl_xor(a, o); b += __shfl_xor(b, o); }
            if (l16 == 0) {
                int row = i * 16 + quad * 4 + r;
                red[row * 4 + wv] = a;
                red[128 + row * 4 + wv] = b;
            }
        }
    __syncthreads();
    {
        float gv[4], bv[4], wh0[4], wh1[4];
#pragma unroll
        for (int j = 0; j < 4; j++) {
            int col = wv * 64 + j * 16 + l16;
            gv[j] = g_f[col]; bv[j] = beta_f[col];
            wh0[j] = Wh[col * 2 + 0]; wh1[j] = Wh[col * 2 + 1];
        }
        float d0v[2][4], d1v[2][4];
#pragma unroll
        for (int i = 0; i < 2; i++)
#pragma unroll
            for (int r = 0; r < 4; r++) {
                int row = i * 16 + quad * 4 + r;
                float4 sv = *(const float4*)&red[row * 4];
                float4 qv = *(const float4*)&red[128 + row * 4];
                float st = sv.x + sv.y + sv.z + sv.w;
                float qt = qv.x + qv.y + qv.z + qv.w;
                float m = st * (1.f / 256.f);
                float rsv = rsqrtf(qt * (1.f / 256.f) - m * m + 1e-5f);
                float d0 = 0.f, d1 = 0.f;
#pragma unroll
                for (int j = 0; j < 4; j++) {
                    float xn = (h_acc[i][j][r] - m) * rsv * gv[j] + bv[j];
                    d0 = fmaf(xn, wh0[j], d0);
                    d1 = fmaf(xn, wh1[j], d1);
                }
#pragma unroll
                for (int o = 1; o < 16; o <<= 1) { d0 += __shfl_xor(d0, o); d1 += __shfl_xor(d1, o); }
                d0v[i][r] = d0; d1v[i][r] = d1;
            }
        __syncthreads();   // all red stat-reads done before overwriting with head partials
#pragma unroll
        for (int i = 0; i < 2; i++)
#pragma unroll
            for (int r = 0; r < 4; r++)
                if (l16 == 0) {
                    int row = i * 16 + quad * 4 + r;
                    red[(row * 4 + wv) * 2 + 0] = d0v[i][r];
                    red[(row * 4 + wv) * 2 + 1] = d1v[i][r];
                }
    }
    __syncthreads();
    if (tid < 64) {
        int row = tid >> 1, o = tid & 1;
        float v = red[(row * 4 + 0) * 2 + o] + red[(row * 4 + 1) * 2 + o]
                + red[(row * 4 + 2) * 2 + o] + red[(row * 4 + 3) * 2 + o];
        out[(size_t)(m0 + row) * 2 + o] = v + bh[o];
    }
}

// ---------------- launch ----------------
extern "C" void kernel_launch(void* const* d_in, const int* in_sizes, int n_in,
                              void* d_out, int out_size, void* d_ws, size_t ws_size,
                              hipStream_t stream)
{
    const float* x_num   = (const float*)d_in[0];
    const int*   cidx    = (const int*)d_in[1];
    const float* w_num   = (const float*)d_in[2];
    const float* b_num   = (const float*)d_in[3];
    const float* cemb    = (const float*)d_in[4];
    const float* W_first = (const float*)d_in[5];
    const float* b_first = (const float*)d_in[6];
    const float* ln_g    = (const float*)d_in[7];
    const float* ln_b    = (const float*)d_in[8];
    const float* W1s     = (const float*)d_in[9];
    const float* b1s     = (const float*)d_in[10];
    const float* W2s     = (const float*)d_in[11];
    const float* b2s     = (const float*)d_in[12];
    const float* g_f     = (const float*)d_in[13];
    const float* beta_f  = (const float*)d_in[14];
    const float* W_head  = (const float*)d_in[15];
    const float* b_head  = (const float*)d_in[16];
    float* out = (float*)d_out;

    char* ws = (char*)d_ws;
    float* U   = (float*)(ws + 0);          //  32 KB
    float* c0  = (float*)(ws + 32768);      //   1 KB
    float* P   = (float*)(ws + 33792);      //  32 KB
    u16* WcT   = (u16*)(ws + 66560);        // 256 x 4160 bf16
    u16* W1T   = (u16*)(ws + 2196480);      // 8 x 512 x 256 bf16
    u16* W2T   = (u16*)(ws + 4293632);      // 8 x 256 x 512 bf16
    // total ~6.4 MB

    prep_u_kernel<<<32, 256, 0, stream>>>(w_num, b_num, W_first, U, P);
    prep_c0_kernel<<<1, 256, 0, stream>>>(b_first, P, c0);
    prep_wcat_kernel<<<4160, 256, 0, stream>>>(W_first, U, WcT);
    prep_w1t_kernel<<<2048, 256, 0, stream>>>(W1s, W1T);
    prep_w2t_kernel<<<4096, 256, 0, stream>>>(W2s, W2T);

    mega_kernel<<<512, 256, 0, stream>>>(
        WcT, c0, cidx, cemb, x_num,
        ln_g, ln_b, W1T, b1s, W2T, b2s,
        g_f, beta_f, W_head, b_head, out);
}

// Round 4
// 638.867 us; speedup vs baseline: 1.2823x; 1.2823x over previous
//
#include <hip/hip_runtime.h>

typedef unsigned short u16;
typedef unsigned int u32;
typedef __attribute__((ext_vector_type(8))) short bf16x8;
typedef __attribute__((ext_vector_type(4))) float f32x4;

#define LDK 72   // stage-1 LDS stride (64 + 8 pad)

__device__ __forceinline__ u16 f2bf(float f) {
    u32 u = __float_as_uint(f);
    u += 0x7fffu + ((u >> 16) & 1u);   // round-to-nearest-even
    return (u16)(u >> 16);
}

// ---------------- prep kernels ----------------

__global__ __launch_bounds__(256) void prep_u_kernel(
    const float* __restrict__ w_num, const float* __restrict__ b_num,
    const float* __restrict__ W_first, float* __restrict__ U, float* __restrict__ P)
{
    __shared__ float wrow[256];
    __shared__ float brow[256];
    int j = threadIdx.x, f = blockIdx.x;
    wrow[j] = w_num[f * 256 + j];
    brow[j] = b_num[f * 256 + j];
    __syncthreads();
    float au = 0.f, ap = 0.f;
    for (int k = 0; k < 256; k++) {
        float w = W_first[(size_t)((f << 8) + k) * 256 + j];
        au = fmaf(wrow[k], w, au);
        ap = fmaf(brow[k], w, ap);
    }
    U[f * 256 + j] = au;
    P[f * 256 + j] = ap;
}

__global__ __launch_bounds__(256) void prep_c0_kernel(
    const float* __restrict__ b_first, const float* __restrict__ P, float* __restrict__ c0)
{
    int j = threadIdx.x;
    float a = b_first[j];
    for (int f = 0; f < 32; f++) a += P[f * 256 + j];
    c0[j] = a;
}

// WcT[j][k] (256 x 4160 bf16): k<4096 -> W_first[8192+k][j]; k<4128 -> U[k-4096][j]; else 0
__global__ __launch_bounds__(256) void prep_wcat_kernel(
    const float* __restrict__ W_first, const float* __restrict__ U, u16* __restrict__ WcT)
{
    int k = blockIdx.x;   // 0..4159
    int j = threadIdx.x;  // 0..255
    float v;
    if (k < 4096)      v = W_first[(size_t)(8192 + k) * 256 + j];
    else if (k < 4128) v = U[(k - 4096) * 256 + j];
    else               v = 0.f;
    WcT[(size_t)j * 4160 + k] = f2bf(v);
}

__global__ __launch_bounds__(256) void prep_w1t_kernel(
    const float* __restrict__ W1s, u16* __restrict__ W1T)
{
    int bk = blockIdx.x;             // l*256 + k
    int l = bk >> 8, k = bk & 255;
    int n = threadIdx.x;
    for (int h = 0; h < 2; h++) {
        int nn = n + h * 256;
        float v = W1s[(size_t)l * 131072 + (size_t)k * 512 + nn];
        W1T[(size_t)l * 131072 + (size_t)nn * 256 + k] = f2bf(v);
    }
}

__global__ __launch_bounds__(256) void prep_w2t_kernel(
    const float* __restrict__ W2s, u16* __restrict__ W2T)
{
    int bk = blockIdx.x;             // l*512 + k
    int l = bk >> 9, k = bk & 511;
    int n = threadIdx.x;
    float v = W2s[(size_t)l * 131072 + (size_t)k * 256 + n];
    W2T[(size_t)l * 131072 + (size_t)n * 512 + k] = f2bf(v);
}

// ---------------- first layer: gathered-A GEMM, BM=32 x full N=256 ----------------
#define FBM 32
__global__ __launch_bounds__(256) void first_gemm_kernel(
    const u16* __restrict__ BT, const float* __restrict__ bias,
    float* __restrict__ outF,
    const int* __restrict__ cidx, const float* __restrict__ cemb,
    const float* __restrict__ xnum)
{
    __shared__ __align__(16) u16 Ab[FBM * LDK];
    __shared__ __align__(16) u16 Bb[256 * LDK];
    __shared__ int   sidx[FBM * 16];
    __shared__ float sx[FBM * 32];

    const int tid = threadIdx.x;
    const int lane = tid & 63;
    const int wv = tid >> 6;
    const int quad = lane >> 4;
    const int l16 = lane & 15;
    const int m0 = blockIdx.x * FBM;

#pragma unroll
    for (int i = 0; i < 2; i++) sidx[tid + i * 256] = cidx[m0 * 16 + tid + i * 256];
    {
        float4 v = *(const float4*)&xnum[(size_t)m0 * 32 + tid * 4];
        sx[tid * 4 + 0] = v.x; sx[tid * 4 + 1] = v.y;
        sx[tid * 4 + 2] = v.z; sx[tid * 4 + 3] = v.w;
    }
    __syncthreads();

    f32x4 acc[2][4];
#pragma unroll
    for (int i = 0; i < 2; i++)
#pragma unroll
        for (int j = 0; j < 4; j++) acc[i][j] = (f32x4){0.f, 0.f, 0.f, 0.f};

    for (int k0 = 0; k0 < 4160; k0 += 64) {
#pragma unroll
        for (int it = 0; it < 2; it++) {
            int chunk = tid + it * 256;   // 512 float4 chunks
            int r = chunk >> 4;
            int c4 = chunk & 15;
            int k = k0 + c4 * 4;
            float4 v;
            if (k < 4096) {
                int f = k >> 8;
                int rowi = sidx[r * 16 + f];
                v = *(const float4*)&cemb[(size_t)rowi * 256 + (k & 255)];
            } else if (k < 4128) {
                int c = k - 4096;
                v.x = sx[r * 32 + c];     v.y = sx[r * 32 + c + 1];
                v.z = sx[r * 32 + c + 2]; v.w = sx[r * 32 + c + 3];
            } else {
                v = make_float4(0.f, 0.f, 0.f, 0.f);
            }
            u16* dst = &Ab[r * LDK + c4 * 4];
            dst[0] = f2bf(v.x); dst[1] = f2bf(v.y);
            dst[2] = f2bf(v.z); dst[3] = f2bf(v.w);
        }
#pragma unroll
        for (int it = 0; it < 8; it++) {
            int chunk = tid + it * 256;   // 2048 chunks of 8 bf16
            int r = chunk >> 3;
            int c8 = chunk & 7;
            *(bf16x8*)&Bb[r * LDK + c8 * 8] =
                *(const bf16x8*)&BT[(size_t)r * 4160 + k0 + c8 * 8];
        }
        __syncthreads();
#pragma unroll
        for (int kk = 0; kk < 64; kk += 32) {
            bf16x8 af[2], bfr[4];
#pragma unroll
            for (int i = 0; i < 2; i++)
                af[i] = *(const bf16x8*)&Ab[(i * 16 + l16) * LDK + kk + quad * 8];
#pragma unroll
            for (int j = 0; j < 4; j++)
                bfr[j] = *(const bf16x8*)&Bb[(wv * 64 + j * 16 + l16) * LDK + kk + quad * 8];
#pragma unroll
            for (int i = 0; i < 2; i++)
#pragma unroll
                for (int j = 0; j < 4; j++)
                    acc[i][j] = __builtin_amdgcn_mfma_f32_16x16x32_bf16(
                        af[i], bfr[j], acc[i][j], 0, 0, 0);
        }
        __syncthreads();
    }

    // C/D layout: col = lane&15, row = (lane>>4)*4 + reg
#pragma unroll
    for (int i = 0; i < 2; i++) {
#pragma unroll
        for (int j = 0; j < 4; j++) {
            int col = wv * 64 + j * 16 + l16;
            float bs = bias[col];
#pragma unroll
            for (int r = 0; r < 4; r++) {
                int row = m0 + i * 16 + quad * 4 + r;
                outF[(size_t)row * 256 + col] = acc[i][j][r] + bs;
            }
        }
    }
}

// ---------------- fused residual layer: LN -> FC1+ReLU -> FC2 + resid ----------------
// One dispatch per layer so this layer's 512 KB of weights stay hot in every XCD L2.
// Block owns 32 rows end-to-end; hn/hid live in LDS; h round-trips HBM once per layer.
__global__ __launch_bounds__(256, 3) void layer_kernel(
    float* __restrict__ h,            // [16384][256] fp32, updated in place
    const float* __restrict__ g,      // ln_g row
    const float* __restrict__ bta,    // ln_b row
    const u16* __restrict__ W1,       // [512][256] bf16 (BT layout)
    const float* __restrict__ b1,     // [512]
    const u16* __restrict__ W2,       // [256][512] bf16 (BT layout)
    const float* __restrict__ b2)     // [256]
{
    __shared__ __align__(16) u16 hn[32 * 264];    // 16896 B
    __shared__ __align__(16) u16 hid[32 * 520];   // 33280 B
    const int tid  = threadIdx.x;
    const int lane = tid & 63;
    const int wv   = tid >> 6;
    const int quad = lane >> 4;
    const int l16  = lane & 15;
    const int m0   = blockIdx.x * 32;

    // ---- phase A: LN (wave per row, 8 rounds) ----
    float4 gv4 = *(const float4*)&g[lane * 4];
    float4 bv4 = *(const float4*)&bta[lane * 4];
#pragma unroll
    for (int rr = 0; rr < 8; rr++) {
        int row = rr * 4 + wv;
        float4 x = *(const float4*)&h[(size_t)(m0 + row) * 256 + lane * 4];
        float s  = x.x + x.y + x.z + x.w;
        float s2 = x.x * x.x + x.y * x.y + x.z * x.z + x.w * x.w;
#pragma unroll
        for (int o = 32; o > 0; o >>= 1) { s += __shfl_xor(s, o); s2 += __shfl_xor(s2, o); }
        float mu = s * (1.f / 256.f);
        float rs = rsqrtf(s2 * (1.f / 256.f) - mu * mu + 1e-5f);
        ushort4 o4;
        o4.x = f2bf((x.x - mu) * rs * gv4.x + bv4.x);
        o4.y = f2bf((x.y - mu) * rs * gv4.y + bv4.y);
        o4.z = f2bf((x.z - mu) * rs * gv4.z + bv4.z);
        o4.w = f2bf((x.w - mu) * rs * gv4.w + bv4.w);
        *(ushort4*)&hn[row * 264 + lane * 4] = o4;
    }
    __syncthreads();

    // ---- phase B: FC1 (wave owns 128 of 512 cols), weights direct from L2 ----
    float b1v[8];
#pragma unroll
    for (int j = 0; j < 8; j++) b1v[j] = b1[wv * 128 + j * 16 + l16];
    f32x4 acc1[2][8];
#pragma unroll
    for (int i = 0; i < 2; i++)
#pragma unroll
        for (int j = 0; j < 8; j++) acc1[i][j] = (f32x4){0.f, 0.f, 0.f, 0.f};
#pragma unroll
    for (int kk = 0; kk < 256; kk += 32) {
        bf16x8 af0 = *(const bf16x8*)&hn[(l16) * 264 + kk + quad * 8];
        bf16x8 af1 = *(const bf16x8*)&hn[(16 + l16) * 264 + kk + quad * 8];
        bf16x8 bw[8];
#pragma unroll
        for (int j = 0; j < 8; j++)
            bw[j] = *(const bf16x8*)&W1[(size_t)(wv * 128 + j * 16 + l16) * 256 + kk + quad * 8];
#pragma unroll
        for (int j = 0; j < 8; j++) {
            acc1[0][j] = __builtin_amdgcn_mfma_f32_16x16x32_bf16(af0, bw[j], acc1[0][j], 0, 0, 0);
            acc1[1][j] = __builtin_amdgcn_mfma_f32_16x16x32_bf16(af1, bw[j], acc1[1][j], 0, 0, 0);
        }
    }
#pragma unroll
    for (int i = 0; i < 2; i++)
#pragma unroll
        for (int j = 0; j < 8; j++)
#pragma unroll
            for (int r = 0; r < 4; r++) {
                float v = acc1[i][j][r] + b1v[j];
                v = v > 0.f ? v : 0.f;
                hid[(i * 16 + quad * 4 + r) * 520 + wv * 128 + j * 16 + l16] = f2bf(v);
            }
    __syncthreads();

    // ---- phase C: FC2 (wave owns 64 of 256 cols) + bias + residual ----
    float b2v[4];
#pragma unroll
    for (int j = 0; j < 4; j++) b2v[j] = b2[wv * 64 + j * 16 + l16];
    f32x4 acc2[2][4];
#pragma unroll
    for (int i = 0; i < 2; i++)
#pragma unroll
        for (int j = 0; j < 4; j++) acc2[i][j] = (f32x4){0.f, 0.f, 0.f, 0.f};
#pragma unroll
    for (int kk = 0; kk < 512; kk += 32) {
        bf16x8 af0 = *(const bf16x8*)&hid[(l16) * 520 + kk + quad * 8];
        bf16x8 af1 = *(const bf16x8*)&hid[(16 + l16) * 520 + kk + quad * 8];
        bf16x8 bw[4];
#pragma unroll
        for (int j = 0; j < 4; j++)
            bw[j] = *(const bf16x8*)&W2[(size_t)(wv * 64 + j * 16 + l16) * 512 + kk + quad * 8];
#pragma unroll
        for (int j = 0; j < 4; j++) {
            acc2[0][j] = __builtin_amdgcn_mfma_f32_16x16x32_bf16(af0, bw[j], acc2[0][j], 0, 0, 0);
            acc2[1][j] = __builtin_amdgcn_mfma_f32_16x16x32_bf16(af1, bw[j], acc2[1][j], 0, 0, 0);
        }
    }
#pragma unroll
    for (int i = 0; i < 2; i++)
#pragma unroll
        for (int j = 0; j < 4; j++) {
            int col = wv * 64 + j * 16 + l16;
#pragma unroll
            for (int r = 0; r < 4; r++) {
                int row = m0 + i * 16 + quad * 4 + r;
                float v = acc2[i][j][r] + b2v[j];
                h[(size_t)row * 256 + col] = v + h[(size_t)row * 256 + col];
            }
        }
}

// ---------------- head: final LN + [256 x 2] matvec ----------------
__global__ __launch_bounds__(256) void head_kernel(
    const float* __restrict__ h, const float* __restrict__ g,
    const float* __restrict__ bta, const float* __restrict__ Wh,
    const float* __restrict__ bh, float* __restrict__ out)
{
    int lane = threadIdx.x & 63;
    int row = blockIdx.x * 4 + (threadIdx.x >> 6);
    const float4 x = *(const float4*)&h[(size_t)row * 256 + lane * 4];
    float s = x.x + x.y + x.z + x.w;
    float s2 = x.x * x.x + x.y * x.y + x.z * x.z + x.w * x.w;
    for (int o = 32; o > 0; o >>= 1) { s += __shfl_xor(s, o); s2 += __shfl_xor(s2, o); }
    float mu = s * (1.f / 256.f);
    float rs = rsqrtf(s2 * (1.f / 256.f) - mu * mu + 1e-5f);
    float4 gv = *(const float4*)&g[lane * 4];
    float4 bv = *(const float4*)&bta[lane * 4];
    float xn0 = (x.x - mu) * rs * gv.x + bv.x;
    float xn1 = (x.y - mu) * rs * gv.y + bv.y;
    float xn2 = (x.z - mu) * rs * gv.z + bv.z;
    float xn3 = (x.w - mu) * rs * gv.w + bv.w;
    float4 wa = *(const float4*)&Wh[lane * 8];
    float4 wb = *(const float4*)&Wh[lane * 8 + 4];
    float d0 = xn0 * wa.x + xn1 * wa.z + xn2 * wb.x + xn3 * wb.z;
    float d1 = xn0 * wa.y + xn1 * wa.w + xn2 * wb.y + xn3 * wb.w;
    for (int o = 32; o > 0; o >>= 1) { d0 += __shfl_xor(d0, o); d1 += __shfl_xor(d1, o); }
    if (lane == 0) {
        out[(size_t)row * 2 + 0] = d0 + bh[0];
        out[(size_t)row * 2 + 1] = d1 + bh[1];
    }
}

// ---------------- launch ----------------
extern "C" void kernel_launch(void* const* d_in, const int* in_sizes, int n_in,
                              void* d_out, int out_size, void* d_ws, size_t ws_size,
                              hipStream_t stream)
{
    const float* x_num   = (const float*)d_in[0];
    const int*   cidx    = (const int*)d_in[1];
    const float* w_num   = (const float*)d_in[2];
    const float* b_num   = (const float*)d_in[3];
    const float* cemb    = (const float*)d_in[4];
    const float* W_first = (const float*)d_in[5];
    const float* b_first = (const float*)d_in[6];
    const float* ln_g    = (const float*)d_in[7];
    const float* ln_b    = (const float*)d_in[8];
    const float* W1s     = (const float*)d_in[9];
    const float* b1s     = (const float*)d_in[10];
    const float* W2s     = (const float*)d_in[11];
    const float* b2s     = (const float*)d_in[12];
    const float* g_f     = (const float*)d_in[13];
    const float* beta_f  = (const float*)d_in[14];
    const float* W_head  = (const float*)d_in[15];
    const float* b_head  = (const float*)d_in[16];
    float* out = (float*)d_out;

    char* ws = (char*)d_ws;
    float* U   = (float*)(ws + 0);          //  32 KB
    float* c0  = (float*)(ws + 32768);      //   1 KB
    float* P   = (float*)(ws + 33792);      //  32 KB
    u16* WcT   = (u16*)(ws + 66560);        // 256 x 4160 bf16
    u16* W1T   = (u16*)(ws + 2196480);      // 8 x 512 x 256 bf16
    u16* W2T   = (u16*)(ws + 4293632);      // 8 x 256 x 512 bf16
    float* h   = (float*)(ws + 6390784);    // 16384 x 256 f32
    // total ~22.4 MB

    prep_u_kernel<<<32, 256, 0, stream>>>(w_num, b_num, W_first, U, P);
    prep_c0_kernel<<<1, 256, 0, stream>>>(b_first, P, c0);
    prep_wcat_kernel<<<4160, 256, 0, stream>>>(W_first, U, WcT);
    prep_w1t_kernel<<<2048, 256, 0, stream>>>(W1s, W1T);
    prep_w2t_kernel<<<4096, 256, 0, stream>>>(W2s, W2T);

    first_gemm_kernel<<<16384 / FBM, 256, 0, stream>>>(
        WcT, c0, h, cidx, cemb, x_num);

    for (int l = 0; l < 8; l++) {
        layer_kernel<<<512, 256, 0, stream>>>(
            h, ln_g + l * 256, ln_b + l * 256,
            W1T + (size_t)l * 131072, b1s + l * 512,
            W2T + (size_t)l * 131072, b2s + l * 256);
    }
    head_kernel<<<4096, 256, 0, stream>>>(h, g_f, beta_f, W_head, b_head, out);
}